// Round 1
// baseline (774.628 us; speedup 1.0000x reference)
//
#include <hip/hip_runtime.h>
#include <math.h>

// Problem constants (fixed shapes from reference):
//   x: [1, 512, 448, 448] fp32; boost_weight: [512, 512] fp32
#define NCH   512
#define HW    200704        // 448*448
#define HW4   50176         // HW/4 (float4 count per channel)
#define X_ELEMS 102760448ULL // 512*200704

// ws layout (floats):
//   [0,512)     x_avr
//   [512,1024)  x_tmp
//   [1024,1536) x_sparse
//   [1536,2048) scale
//   [2048]      inv_norm (1.0 if norm not finite/positive)

// ---------------------------------------------------------------------------
// Kernel 1: per-channel mean. One block per channel, 512 threads, float4.
// ---------------------------------------------------------------------------
__global__ __launch_bounds__(512) void k_channel_mean(const float* __restrict__ x,
                                                      float* __restrict__ ws) {
    __shared__ float red[8];
    const int c = blockIdx.x;
    const float4* xv = reinterpret_cast<const float4*>(x) + (size_t)c * HW4;
    float s = 0.f;
    // 50176 / 512 = 98 iterations, fully coalesced streaming
    #pragma unroll 4
    for (int i = threadIdx.x; i < HW4; i += 512) {
        float4 v = xv[i];
        s += (v.x + v.y) + (v.z + v.w);
    }
    #pragma unroll
    for (int o = 32; o > 0; o >>= 1) s += __shfl_down(s, o, 64);
    const int wave = threadIdx.x >> 6;
    const int lane = threadIdx.x & 63;
    if (lane == 0) red[wave] = s;
    __syncthreads();
    if (threadIdx.x == 0) {
        float t = 0.f;
        #pragma unroll
        for (int w = 0; w < 8; ++w) t += red[w];
        ws[c] = t * (1.0f / (float)HW);
    }
}

// ---------------------------------------------------------------------------
// Kernel 2: all the tiny per-channel stats in one 512-thread block.
// ---------------------------------------------------------------------------
__global__ __launch_bounds__(512) void k_stats(const float* __restrict__ W,
                                               float* __restrict__ ws) {
    __shared__ float avr[512];
    __shared__ float red[8];
    __shared__ float redA[8], redB[8], redD[8];
    __shared__ float bcast;

    const int t = threadIdx.x;
    const int wave = t >> 6;
    const int lane = t & 63;

    avr[t] = ws[t];
    __syncthreads();

    // boost_vec[t] = W[t,:] dot x_avr  (W = 1 MB, fits in L2; negligible time)
    float acc = 0.f;
    const float* row = W + (size_t)t * NCH;
    #pragma unroll 8
    for (int j = 0; j < NCH; ++j) acc += row[j] * avr[j];

    // inh = mean(boost_vec)
    float s = acc;
    #pragma unroll
    for (int o = 32; o > 0; o >>= 1) s += __shfl_down(s, o, 64);
    if (lane == 0) red[wave] = s;
    __syncthreads();
    if (t == 0) {
        float tt = 0.f;
        #pragma unroll
        for (int w = 0; w < 8; ++w) tt += red[w];
        bcast = tt * (1.0f / (float)NCH);
    }
    __syncthreads();
    const float inh = bcast;

    // x_tmp = relu(x_avr + boost_vec - 2*inh)
    float xtmp = avr[t] + acc - 2.0f * inh;
    xtmp = xtmp > 0.f ? xtmp : 0.f;

    // threshold = max(x_tmp) * 0.9
    float m = xtmp;
    #pragma unroll
    for (int o = 32; o > 0; o >>= 1) m = fmaxf(m, __shfl_down(m, o, 64));
    __syncthreads();               // red reuse + bcast reuse fence
    if (lane == 0) red[wave] = m;
    __syncthreads();
    if (t == 0) {
        float mm = red[0];
        #pragma unroll
        for (int w = 1; w < 8; ++w) mm = fmaxf(mm, red[w]);
        bcast = mm * 0.9f;
    }
    __syncthreads();
    const float thr = bcast;
    const float xs = (xtmp < thr) ? 0.f : xtmp;

    // Frobenius norm of outer(x_tmp,x_sparse) with zeroed diagonal, factored:
    //   norm^2 = (sum xt^2)(sum xs^2) - sum (xt*xs)^2
    float a = xtmp * xtmp;
    float b = xs * xs;
    float d = xtmp * xs; d = d * d;
    #pragma unroll
    for (int o = 32; o > 0; o >>= 1) {
        a += __shfl_down(a, o, 64);
        b += __shfl_down(b, o, 64);
        d += __shfl_down(d, o, 64);
    }
    if (lane == 0) { redA[wave] = a; redB[wave] = b; redD[wave] = d; }
    __syncthreads();
    if (t == 0) {
        float s1 = 0.f, s2 = 0.f, s3 = 0.f;
        #pragma unroll
        for (int w = 0; w < 8; ++w) { s1 += redA[w]; s2 += redB[w]; s3 += redD[w]; }
        float n2 = s1 * s2 - s3;
        float norm = (n2 > 0.f) ? sqrtf(n2) : 0.f;
        float inv = (norm > 0.f && isfinite(norm)) ? (1.0f / norm) : 1.0f;
        ws[2048] = inv;
    }

    ws[512 + t]  = xtmp;
    ws[1024 + t] = xs;
    ws[1536 + t] = xtmp / (avr[t] + 1e-12f);
}

// ---------------------------------------------------------------------------
// Kernel 3: new_boost_weight = 0.5*W + 0.05 * (outer(x_tmp,x_sparse)/norm, diag=0)
// 262144 elements; i constant within a block (scalar broadcast), j coalesced.
// ---------------------------------------------------------------------------
__global__ __launch_bounds__(256) void k_weight_update(const float* __restrict__ W,
                                                       const float* __restrict__ ws,
                                                       float* __restrict__ outW) {
    const int idx = blockIdx.x * 256 + threadIdx.x;
    const int i = idx >> 9;
    const int j = idx & (NCH - 1);
    const float inv = ws[2048];
    const float v = (i == j) ? 0.f : ws[512 + i] * ws[1024 + j] * inv;
    outW[idx] = 0.5f * W[idx] + 0.05f * v;
}

// ---------------------------------------------------------------------------
// Kernel 4: out = x * scale[c], float4, channel index from blockIdx.y (no div).
// grid (49, 512), 256 threads, 4 float4 per thread: 49*4*256 = 50176 = HW4.
// ---------------------------------------------------------------------------
__global__ __launch_bounds__(256) void k_scale(const float* __restrict__ x,
                                               const float* __restrict__ ws,
                                               float* __restrict__ out) {
    const int c = blockIdx.y;
    const float s = ws[1536 + c];
    const size_t chan_base = (size_t)c * HW4;
    const int base = blockIdx.x * 1024 + threadIdx.x;
    const float4* xv = reinterpret_cast<const float4*>(x);
    float4* ov = reinterpret_cast<float4*>(out);
    #pragma unroll
    for (int k = 0; k < 4; ++k) {
        const size_t off = chan_base + (size_t)(base + k * 256);
        float4 v = xv[off];
        v.x *= s; v.y *= s; v.z *= s; v.w *= s;
        ov[off] = v;
    }
}

extern "C" void kernel_launch(void* const* d_in, const int* in_sizes, int n_in,
                              void* d_out, int out_size, void* d_ws, size_t ws_size,
                              hipStream_t stream) {
    const float* x = (const float*)d_in[0];
    const float* W = (const float*)d_in[1];
    float* out  = (float*)d_out;
    float* outW = out + X_ELEMS;   // new_boost_weight follows out in flat order
    float* ws   = (float*)d_ws;

    k_channel_mean<<<NCH, 512, 0, stream>>>(x, ws);
    k_stats<<<1, 512, 0, stream>>>(W, ws);
    k_weight_update<<<(NCH * NCH) / 256, 256, 0, stream>>>(W, ws, outW);
    dim3 grid_scale(49, NCH);
    k_scale<<<grid_scale, 256, 0, stream>>>(x, ws, out);
}

// Round 2
// 757.520 us; speedup vs baseline: 1.0226x; 1.0226x over previous
//
#include <hip/hip_runtime.h>
#include <math.h>

// Problem constants (fixed shapes from reference):
//   x: [1, 512, 448, 448] fp32; boost_weight: [512, 512] fp32
#define NCH    512
#define HW     200704        // 448*448
#define HW4    50176         // HW/4 (float4 per channel)
#define GROUPS 8
#define G4     6272          // HW4/GROUPS
#define X_ELEMS 102760448ULL // 512*200704

// ws layout (floats):
//   [0,4096)      per-(group,channel) partial sums, layout [g*512 + c]
//   [4096,4608)   x_tmp
//   [4608,5120)   x_sparse
//   [5120,5632)   scale
//   [5632]        inv_norm (1.0 if norm not finite/positive)
#define WS_XTMP  4096
#define WS_XSP   4608
#define WS_SCALE 5120
#define WS_INV   5632

typedef float vf4 __attribute__((ext_vector_type(4)));

// ---------------------------------------------------------------------------
// Kernel 1: per-channel partial sums. grid (8, 512), 256 threads.
// Reads x start->end so the TAIL of x is L3-resident when the scale pass
// (which walks channels in reverse) starts.
// ---------------------------------------------------------------------------
__global__ __launch_bounds__(256) void k_mean_partial(const float* __restrict__ x,
                                                      float* __restrict__ ws) {
    __shared__ float red[4];
    const int g = blockIdx.x;   // 0..7
    const int c = blockIdx.y;   // 0..511
    const float4* xv = reinterpret_cast<const float4*>(x) + (size_t)c * HW4 + (size_t)g * G4;
    float s = 0.f;
    // 6272 / 256 = 24.5 iterations, coalesced streaming
    for (int i = threadIdx.x; i < G4; i += 256) {
        float4 v = xv[i];
        s += (v.x + v.y) + (v.z + v.w);
    }
    #pragma unroll
    for (int o = 32; o > 0; o >>= 1) s += __shfl_down(s, o, 64);
    const int wave = threadIdx.x >> 6;
    const int lane = threadIdx.x & 63;
    if (lane == 0) red[wave] = s;
    __syncthreads();
    if (threadIdx.x == 0) {
        ws[g * NCH + c] = (red[0] + red[1]) + (red[2] + red[3]);
    }
}

// ---------------------------------------------------------------------------
// Kernel 2: all the tiny per-channel stats in one 512-thread block.
// ---------------------------------------------------------------------------
__global__ __launch_bounds__(512) void k_stats(const float* __restrict__ W,
                                               float* __restrict__ ws) {
    __shared__ float avr[512];
    __shared__ float red[8];
    __shared__ float redA[8], redB[8], redD[8];
    __shared__ float bcast;

    const int t = threadIdx.x;
    const int wave = t >> 6;
    const int lane = t & 63;

    // finalize channel mean from the 8 partials (coalesced per g)
    {
        float s = 0.f;
        #pragma unroll
        for (int g = 0; g < GROUPS; ++g) s += ws[g * NCH + t];
        avr[t] = s * (1.0f / (float)HW);
    }
    __syncthreads();

    // boost_vec[t] = W[t,:] dot x_avr  (W = 1 MB; negligible)
    float acc = 0.f;
    const float* row = W + (size_t)t * NCH;
    #pragma unroll 8
    for (int j = 0; j < NCH; ++j) acc += row[j] * avr[j];

    // inh = mean(boost_vec)
    float s = acc;
    #pragma unroll
    for (int o = 32; o > 0; o >>= 1) s += __shfl_down(s, o, 64);
    if (lane == 0) red[wave] = s;
    __syncthreads();
    if (t == 0) {
        float tt = 0.f;
        #pragma unroll
        for (int w = 0; w < 8; ++w) tt += red[w];
        bcast = tt * (1.0f / (float)NCH);
    }
    __syncthreads();
    const float inh = bcast;

    // x_tmp = relu(x_avr + boost_vec - 2*inh)
    float xtmp = avr[t] + acc - 2.0f * inh;
    xtmp = xtmp > 0.f ? xtmp : 0.f;

    // threshold = max(x_tmp) * 0.9
    float m = xtmp;
    #pragma unroll
    for (int o = 32; o > 0; o >>= 1) m = fmaxf(m, __shfl_down(m, o, 64));
    __syncthreads();               // red/bcast reuse fence
    if (lane == 0) red[wave] = m;
    __syncthreads();
    if (t == 0) {
        float mm = red[0];
        #pragma unroll
        for (int w = 1; w < 8; ++w) mm = fmaxf(mm, red[w]);
        bcast = mm * 0.9f;
    }
    __syncthreads();
    const float thr = bcast;
    const float xs = (xtmp < thr) ? 0.f : xtmp;

    // Frobenius norm of outer(x_tmp,x_sparse) with zeroed diagonal, factored:
    //   norm^2 = (sum xt^2)(sum xs^2) - sum (xt*xs)^2
    float a = xtmp * xtmp;
    float b = xs * xs;
    float d = xtmp * xs; d = d * d;
    #pragma unroll
    for (int o = 32; o > 0; o >>= 1) {
        a += __shfl_down(a, o, 64);
        b += __shfl_down(b, o, 64);
        d += __shfl_down(d, o, 64);
    }
    if (lane == 0) { redA[wave] = a; redB[wave] = b; redD[wave] = d; }
    __syncthreads();
    if (t == 0) {
        float s1 = 0.f, s2 = 0.f, s3 = 0.f;
        #pragma unroll
        for (int w = 0; w < 8; ++w) { s1 += redA[w]; s2 += redB[w]; s3 += redD[w]; }
        float n2 = s1 * s2 - s3;
        float norm = (n2 > 0.f) ? sqrtf(n2) : 0.f;
        float inv = (norm > 0.f && isfinite(norm)) ? (1.0f / norm) : 1.0f;
        ws[WS_INV] = inv;
    }

    ws[WS_XTMP + t]  = xtmp;
    ws[WS_XSP + t]   = xs;
    ws[WS_SCALE + t] = xtmp / (avr[t] + 1e-12f);
}

// ---------------------------------------------------------------------------
// Kernel 3 (fused tail): blocks [0,1024) -> weight update; rest -> rescale.
// Rescale walks channels in REVERSE so the L3-resident tail of x (just read
// by the mean pass) is consumed before eviction. Nontemporal stores keep the
// 411 MB output stream from thrashing the cached x.
// ---------------------------------------------------------------------------
__global__ __launch_bounds__(256) void k_tail(const float* __restrict__ x,
                                              const float* __restrict__ W,
                                              const float* __restrict__ ws,
                                              float* __restrict__ out,
                                              float* __restrict__ outW) {
    const int bid = blockIdx.x;
    if (bid < 1024) {
        // new_boost_weight = 0.5*W + 0.05 * (outer(x_tmp,x_sparse)/norm, diag=0)
        const int idx = bid * 256 + threadIdx.x;
        const int i = idx >> 9;
        const int j = idx & (NCH - 1);
        const float inv = ws[WS_INV];
        const float v = (i == j) ? 0.f : ws[WS_XTMP + i] * ws[WS_XSP + j] * inv;
        outW[idx] = 0.5f * W[idx] + 0.05f * v;
    } else {
        const int b = bid - 1024;           // 0..25087
        const int c_lin = b / 49;           // 0..511 (blocks dispatch ~in order)
        const int t = b - c_lin * 49;       // 0..48
        const int c = (NCH - 1) - c_lin;    // reverse: L3-hottest channels first
        const float s = ws[WS_SCALE + c];
        const size_t chan_base = (size_t)c * HW4;
        const int base = t * 1024 + threadIdx.x;
        const float4* xv = reinterpret_cast<const float4*>(x);
        float4* ov = reinterpret_cast<float4*>(out);
        #pragma unroll
        for (int k = 0; k < 4; ++k) {
            const size_t off = chan_base + (size_t)(base + k * 256);
            float4 v = xv[off];
            v.x *= s; v.y *= s; v.z *= s; v.w *= s;
            __builtin_nontemporal_store(*(const vf4*)&v, (vf4*)&ov[off]);
        }
    }
}

extern "C" void kernel_launch(void* const* d_in, const int* in_sizes, int n_in,
                              void* d_out, int out_size, void* d_ws, size_t ws_size,
                              hipStream_t stream) {
    const float* x = (const float*)d_in[0];
    const float* W = (const float*)d_in[1];
    float* out  = (float*)d_out;
    float* outW = out + X_ELEMS;   // new_boost_weight follows out in flat order
    float* ws   = (float*)d_ws;

    dim3 grid_mean(GROUPS, NCH);
    k_mean_partial<<<grid_mean, 256, 0, stream>>>(x, ws);
    k_stats<<<1, 512, 0, stream>>>(W, ws);
    k_tail<<<1024 + 49 * NCH, 256, 0, stream>>>(x, W, ws, out, outW);
}